// Round 15
// baseline (155.402 us; speedup 1.0000x reference)
//
#include <hip/hip_runtime.h>
#include <hip/hip_bf16.h>
#include <stdint.h>

#define DIM_ 1024
#define NH_ 16
#define HD_ 64
#define B_ 4
#define S_ 2048
#define SC_ 1024
#define CD_ 768

typedef __attribute__((ext_vector_type(8))) short bf16x8;
typedef __attribute__((ext_vector_type(4))) short bf16x4;
typedef __attribute__((ext_vector_type(4))) float f32x4;

// native bf16 cast (RTNE) -- compiler lowers pairs to v_cvt_pk_bf16_f32
__device__ inline unsigned short f2bf(float f) {
    __hip_bfloat16 h = __float2bfloat16(f);
    return __builtin_bit_cast(unsigned short, h);
}

__device__ inline f32x4 vmax4(f32x4 a, f32x4 b) {
    f32x4 r;
#pragma unroll
    for (int i = 0; i < 4; ++i) r[i] = fmaxf(a[i], b[i]);
    return r;
}

#define GLOAD16(SRC, DST) __builtin_amdgcn_global_load_lds( \
    (const __attribute__((address_space(1))) void*)(SRC),   \
    (__attribute__((address_space(3))) void*)(DST), 16, 0, 0)

// ---------------- fused prep: x/cx -> bf16, 4 weight transposes, mask bits ----------------
__global__ void k_prep(const float* __restrict__ x, unsigned short* __restrict__ xb,
                       const float* __restrict__ cx, unsigned short* __restrict__ cxb,
                       const float* __restrict__ Wq, const float* __restrict__ Wk,
                       const float* __restrict__ Wv, const float* __restrict__ Wo,
                       unsigned short* __restrict__ WQT, unsigned short* __restrict__ WKT,
                       unsigned short* __restrict__ WVT, unsigned short* __restrict__ WOT,
                       const unsigned int* __restrict__ m,
                       unsigned int* __restrict__ bits, int* __restrict__ ntp) {
    const int bid = blockIdx.x;
    if (bid < 11264) {  // f32 -> bf16 conversions (uint2 per thread)
        const float* in; unsigned short* out; int i;
        if (bid < 8192) { in = x;  out = xb;  i = bid * 256 + threadIdx.x; }
        else            { in = cx; out = cxb; i = (bid - 8192) * 256 + threadIdx.x; }
        float4 v = ((const float4*)in)[i];
        uint2 pk;
        pk.x = (unsigned int)f2bf(v.x) | ((unsigned int)f2bf(v.y) << 16);
        pk.y = (unsigned int)f2bf(v.z) | ((unsigned int)f2bf(v.w) << 16);
        ((uint2*)out)[i] = pk;
        return;
    }
    if (bid < 13056) {  // weight transposes: one 16B output chunk per thread
        int idx = (bid - 11264) * 256 + threadIdx.x;
        const float* W; unsigned short* WT; int K;
        if (idx < 131072)      { W = Wq; WT = WQT; K = 1024; }
        else if (idx < 229376) { W = Wk; WT = WKT; K = 768;  idx -= 131072; }
        else if (idx < 327680) { W = Wv; WT = WVT; K = 768;  idx -= 229376; }
        else                   { W = Wo; WT = WOT; K = 1024; idx -= 327680; }
        int n = idx & 1023;
        int k0 = (idx >> 10) << 3;
        unsigned int pk[4];
#pragma unroll
        for (int j = 0; j < 4; ++j) {
            unsigned short a = f2bf(W[(size_t)(k0 + 2 * j) * 1024 + n]);
            unsigned short b = f2bf(W[(size_t)(k0 + 2 * j + 1) * 1024 + n]);
            pk[j] = (unsigned int)a | ((unsigned int)b << 16);
        }
        *(uint4*)&WT[(size_t)n * K + k0] = *(uint4*)pk;
        return;
    }
    // mask block: bitmask + nt[b]
    __shared__ int bm_s;
    __shared__ unsigned int wbits[128];
    if (threadIdx.x == 0) bm_s = 0;
    __syncthreads();
    int any = 0;
    for (int i = threadIdx.x; i < 1024; i += 256)  // first 4096 bytes: safe both modes
        if (m[i] > 1u) any = 1;
    if (any) atomicOr(&bm_s, 1);
    __syncthreads();
    const int boolmode = bm_s;
    const int w = threadIdx.x;
    if (w < 128) {
        const unsigned char* mb = (const unsigned char*)m;
        unsigned int out = 0;
        for (int j = 0; j < 32; ++j) {
            int c = w * 32 + j;
            int masked = boolmode ? (mb[c] != 0) : (m[c] != 0u);
            out |= (unsigned int)masked << j;
        }
        bits[w] = out;
        wbits[w] = out;
    }
    __syncthreads();
    if (threadIdx.x < 4) {
        int nt = 0;
        for (int tt = 0; tt < 16; ++tt) {
            unsigned int w0 = wbits[threadIdx.x * 32 + tt * 2];
            unsigned int w1 = wbits[threadIdx.x * 32 + tt * 2 + 1];
            if ((w0 & w1) != 0xFFFFFFFFu) nt = tt + 1;  // tile has >=1 valid key
        }
        ntp[threadIdx.x] = nt;
    }
}

// ---------------- fused Q + K|V GEMM (one launch, 1024 blocks) ----------------
__global__ __launch_bounds__(256) void k_gemm_qkv(
    const unsigned short* __restrict__ xb, const unsigned short* __restrict__ cxb,
    const unsigned short* __restrict__ wqt, const unsigned short* __restrict__ wkt,
    const float* __restrict__ bq, const float* __restrict__ bk, const float* __restrict__ bv,
    float qscale, unsigned short* __restrict__ qb, unsigned short* __restrict__ kb,
    unsigned short* __restrict__ vtb)
{
    __shared__ unsigned short As[2][128 * 64];
    __shared__ unsigned short Bs[2][128 * 64];
    const int t = threadIdx.x;
    const int w = t >> 6, lane = t & 63;
    const int lo = lane & 15, hi = lane >> 4;
    const int l7 = lo & 7;
    const int wg = blockIdx.x;
    const int swz = (wg & 7) * 128 + (wg >> 3);   // 1024 blocks, bijective
    const bool isQ = !(swz & 1);
    const int lw = swz >> 1;                       // 0..511 per kind
    const int gx = isQ ? 64 : 32;
    const unsigned short* A  = isQ ? xb  : cxb;
    const unsigned short* BT = isQ ? wqt : wkt;
    const int K = isQ ? 1024 : 768;
    const int m0 = (lw % gx) * 128, n0 = (lw / gx) * 128;
    const int wr = (w >> 1) * 64, wc = (w & 1) * 64;
    const int srow = lane >> 3;
    const int scb  = ((lane & 7) ^ srow) << 3;

    f32x4 zero4 = {0.f, 0.f, 0.f, 0.f};
    f32x4 acc[4][4];
    for (int i = 0; i < 4; ++i)
        for (int j = 0; j < 4; ++j) acc[i][j] = zero4;

#pragma unroll
    for (int p = 0; p < 4; ++p) {
        int rb = w * 32 + p * 8;
        GLOAD16(&A[(size_t)(m0 + rb + srow) * K + scb], &As[0][rb * 64]);
        GLOAD16(&BT[(size_t)(n0 + rb + srow) * K + scb], &Bs[0][rb * 64]);
    }
    __syncthreads();

    int cur = 0;
    for (int k0 = 0; k0 < K; k0 += 64) {
        if (k0 + 64 < K) {
#pragma unroll
            for (int p = 0; p < 4; ++p) {
                int rb = w * 32 + p * 8;
                GLOAD16(&A[(size_t)(m0 + rb + srow) * K + k0 + 64 + scb], &As[cur ^ 1][rb * 64]);
                GLOAD16(&BT[(size_t)(n0 + rb + srow) * K + k0 + 64 + scb], &Bs[cur ^ 1][rb * 64]);
            }
        }
#pragma unroll
        for (int kk = 0; kk < 2; ++kk) {
            bf16x8 af[4], bfr[4];
#pragma unroll
            for (int i = 0; i < 4; ++i) {
                int row = wr + i * 16 + lo;
                af[i] = *(const bf16x8*)&As[cur][row * 64 + ((((kk << 2) + hi) ^ l7) << 3)];
            }
#pragma unroll
            for (int j = 0; j < 4; ++j) {
                int row = wc + j * 16 + lo;
                bfr[j] = *(const bf16x8*)&Bs[cur][row * 64 + ((((kk << 2) + hi) ^ l7) << 3)];
            }
#pragma unroll
            for (int i = 0; i < 4; ++i)
#pragma unroll
                for (int j = 0; j < 4; ++j)
                    acc[i][j] = __builtin_amdgcn_mfma_f32_16x16x32_bf16(af[i], bfr[j], acc[i][j], 0, 0, 0);
        }
        __syncthreads();
        cur ^= 1;
    }

#pragma unroll
    for (int i = 0; i < 4; ++i) {
#pragma unroll
        for (int j = 0; j < 4; ++j) {
            int n = n0 + wc + j * 16 + lo;
            int mbase = m0 + wr + i * 16 + (hi << 2);
            if (isQ) {
#pragma unroll
                for (int r = 0; r < 4; ++r) {
                    float v = (acc[i][j][r] + bq[n]) * qscale;
                    qb[(size_t)(mbase + r) * 1024 + n] = f2bf(v);
                }
            } else if (n < 1024) {  // K half
#pragma unroll
                for (int r = 0; r < 4; ++r) {
                    float v = acc[i][j][r] + bk[n];
                    kb[(size_t)(mbase + r) * 1024 + n] = f2bf(v);
                }
            } else {                // V^T half: packed 8B store (4 consecutive c)
                float b2 = bv[n - 1024];
                uint2 pk;
                pk.x = (unsigned int)f2bf(acc[i][j][0] + b2) | ((unsigned int)f2bf(acc[i][j][1] + b2) << 16);
                pk.y = (unsigned int)f2bf(acc[i][j][2] + b2) | ((unsigned int)f2bf(acc[i][j][3] + b2) << 16);
                int bb = mbase >> 10, c = mbase & 1023;
                *(uint2*)&vtb[(size_t)((bb << 10) + (n - 1024)) * 1024 + c] = pk;
            }
        }
    }
}

// ---------------- O GEMM (f32 out), BK=64 XOR-swizzled ----------------
__global__ __launch_bounds__(256) void k_gemm_o(
    const unsigned short* __restrict__ A, const unsigned short* __restrict__ BT,
    const float* __restrict__ bias, float* __restrict__ Cf, int K)
{
    __shared__ unsigned short As[2][128 * 64];
    __shared__ unsigned short Bs[2][128 * 64];
    const int t = threadIdx.x;
    const int w = t >> 6, lane = t & 63;
    const int lo = lane & 15, hi = lane >> 4;
    const int l7 = lo & 7;
    const int nwg = gridDim.x * gridDim.y;
    const int wg = blockIdx.y * gridDim.x + blockIdx.x;
    const int swz = (wg & 7) * (nwg >> 3) + (wg >> 3);
    const int m0 = (swz % gridDim.x) * 128, n0 = (swz / gridDim.x) * 128;
    const int wr = (w >> 1) * 64, wc = (w & 1) * 64;
    const int srow = lane >> 3;
    const int scb  = ((lane & 7) ^ srow) << 3;

    f32x4 zero4 = {0.f, 0.f, 0.f, 0.f};
    f32x4 acc[4][4];
    for (int i = 0; i < 4; ++i)
        for (int j = 0; j < 4; ++j) acc[i][j] = zero4;

#pragma unroll
    for (int p = 0; p < 4; ++p) {
        int rb = w * 32 + p * 8;
        GLOAD16(&A[(size_t)(m0 + rb + srow) * K + scb], &As[0][rb * 64]);
        GLOAD16(&BT[(size_t)(n0 + rb + srow) * K + scb], &Bs[0][rb * 64]);
    }
    __syncthreads();

    int cur = 0;
    for (int k0 = 0; k0 < K; k0 += 64) {
        if (k0 + 64 < K) {
#pragma unroll
            for (int p = 0; p < 4; ++p) {
                int rb = w * 32 + p * 8;
                GLOAD16(&A[(size_t)(m0 + rb + srow) * K + k0 + 64 + scb], &As[cur ^ 1][rb * 64]);
                GLOAD16(&BT[(size_t)(n0 + rb + srow) * K + k0 + 64 + scb], &Bs[cur ^ 1][rb * 64]);
            }
        }
#pragma unroll
        for (int kk = 0; kk < 2; ++kk) {
            bf16x8 af[4], bfr[4];
#pragma unroll
            for (int i = 0; i < 4; ++i) {
                int row = wr + i * 16 + lo;
                af[i] = *(const bf16x8*)&As[cur][row * 64 + ((((kk << 2) + hi) ^ l7) << 3)];
            }
#pragma unroll
            for (int j = 0; j < 4; ++j) {
                int row = wc + j * 16 + lo;
                bfr[j] = *(const bf16x8*)&Bs[cur][row * 64 + ((((kk << 2) + hi) ^ l7) << 3)];
            }
#pragma unroll
            for (int i = 0; i < 4; ++i)
#pragma unroll
                for (int j = 0; j < 4; ++j)
                    acc[i][j] = __builtin_amdgcn_mfma_f32_16x16x32_bf16(af[i], bfr[j], acc[i][j], 0, 0, 0);
        }
        __syncthreads();
        cur ^= 1;
    }

#pragma unroll
    for (int i = 0; i < 4; ++i)
#pragma unroll
        for (int j = 0; j < 4; ++j) {
            int n = n0 + wc + j * 16 + lo;
            int mbase = m0 + wr + i * 16 + (hi << 2);
#pragma unroll
            for (int r = 0; r < 4; ++r)
                Cf[(size_t)(mbase + r) * 1024 + n] = acc[i][j][r] + bias[n];
        }
}

// ---------------- fused flash attention: 8 waves x 32 q-rows, counted-vmcnt pipeline ----------------
// Triple-buffered K/V, prefetch distance 2, raw s_barrier + counted s_waitcnt vmcnt(N)
// (never 0 mid-loop): tile t+1's loads get a full tile of compute to land while
// tile t+2's stay in flight across the barrier. Per-wave math identical to R14.
// Safety: all ds_reads are consumed by MFMAs before each barrier (lgkmcnt-ordered);
// a buffer is rewritten only 3 tiles later, behind 3 barriers; "memory" clobber
// keeps post-barrier ds_reads from hoisting above the vmcnt wait.
__global__ __launch_bounds__(512) void k_attn(
    const unsigned short* __restrict__ Q, const unsigned short* __restrict__ Kb,
    const unsigned short* __restrict__ VT, const unsigned int* __restrict__ bits,
    const int* __restrict__ ntp, unsigned short* __restrict__ Ob)
{
    __shared__ unsigned short lds[24576];  // K: 3 x 4096 @ 0; V: 3 x 4096 @ 12288; epilogue reuses [0,18432)
    const int t = threadIdx.x, w = t >> 6, lane = t & 63;
    const int lo = lane & 15, hi = lane >> 4;
    const int qt = blockIdx.x, h = blockIdx.y, b = blockIdx.z;
    const int qr0 = qt * 256 + w * 32;
    const int l7 = lo & 7;
    const int nt = ntp[b];

    const int srow = lane >> 3;                 // 0..7 within the wave's 8-row pass
    const int scb  = ((lane & 7) ^ srow) << 3;  // pre-swizzled source 16B block
    const int rl = w * 8 + srow;                // this wave's staging row within the tile

    bf16x8 qf[2][2];
#pragma unroll
    for (int qh = 0; qh < 2; ++qh)
#pragma unroll
        for (int kk = 0; kk < 2; ++kk)
            qf[qh][kk] = *(const bf16x8*)&Q[(size_t)(b * S_ + qr0 + qh * 16 + lo) * DIM_ + h * 64 + kk * 32 + hi * 8];

    f32x4 zero4 = {0.f, 0.f, 0.f, 0.f};
    float mrow[2] = {-1e30f, -1e30f}, lsum[2] = {0.f, 0.f};
    f32x4 o[4][2];
#pragma unroll
    for (int dt = 0; dt < 4; ++dt)
#pragma unroll
        for (int qh = 0; qh < 2; ++qh) o[dt][qh] = zero4;

    // prologue: issue tiles 0 and 1 (nt >= 8 always); wait only for tile 0 (vmcnt(2))
    GLOAD16(&Kb[(size_t)(b * SC_ + rl) * DIM_ + h * 64 + scb], &lds[(w * 8) * 64]);
    GLOAD16(&VT[(size_t)(b * 1024 + h * 64 + rl) * SC_ + scb], &lds[12288 + (w * 8) * 64]);
    GLOAD16(&Kb[(size_t)(b * SC_ + 64 + rl) * DIM_ + h * 64 + scb], &lds[4096 + (w * 8) * 64]);
    GLOAD16(&VT[(size_t)(b * 1024 + h * 64 + rl) * SC_ + 64 + scb], &lds[12288 + 4096 + (w * 8) * 64]);
    asm volatile("s_waitcnt vmcnt(2)" ::: "memory");
    __builtin_amdgcn_s_barrier();

    for (int tt = 0; tt < nt; ++tt) {
        const int cur = tt % 3;
        const bool issue = (tt + 2 < nt);
        if (issue) {  // stage tile tt+2 into buf (tt+2)%3 (rewrites buf last read at tt-1)
            int c0n = (tt + 2) * 64;
            int nb = (tt + 2) % 3;
            GLOAD16(&Kb[(size_t)(b * SC_ + c0n + rl) * DIM_ + h * 64 + scb],
                    &lds[nb * 4096 + (w * 8) * 64]);
            GLOAD16(&VT[(size_t)(b * 1024 + h * 64 + rl) * SC_ + c0n + scb],
                    &lds[12288 + nb * 4096 + (w * 8) * 64]);
        }
        const unsigned short* Kl = &lds[cur * 4096];
        const unsigned short* Vl = &lds[12288 + cur * 4096];

        f32x4 st[4][2];
#pragma unroll
        for (int n = 0; n < 4; ++n)
#pragma unroll
            for (int qh = 0; qh < 2; ++qh) st[n][qh] = zero4;
#pragma unroll
        for (int n = 0; n < 4; ++n) {
            const int R = n * 16 + lo;
            bf16x8 k0 = *(const bf16x8*)&Kl[R * 64 + ((hi ^ l7) << 3)];
            bf16x8 k1 = *(const bf16x8*)&Kl[R * 64 + (((4 + hi) ^ l7) << 3)];
#pragma unroll
            for (int qh = 0; qh < 2; ++qh) {
                st[n][qh] = __builtin_amdgcn_mfma_f32_16x16x32_bf16(k0, qf[qh][0], st[n][qh], 0, 0, 0);
                st[n][qh] = __builtin_amdgcn_mfma_f32_16x16x32_bf16(k1, qf[qh][1], st[n][qh], 0, 0, 0);
            }
        }
        bf16x4 vf[4][4];
#pragma unroll
        for (int dt = 0; dt < 4; ++dt)
#pragma unroll
            for (int n = 0; n < 4; ++n)
                vf[dt][n] = *(const bf16x4*)&Vl[(dt * 16 + lo) * 64
                              + (((2 * n + (hi >> 1)) ^ l7) << 3) + ((hi & 1) << 2)];

        uint2 mw = *(const uint2*)&bits[b * 32 + tt * 2];

        f32x4 p[2][4];
        float mx[2];
        if ((mw.x | mw.y) == 0u) {
#pragma unroll
            for (int qh = 0; qh < 2; ++qh) {
                f32x4 a = vmax4(vmax4(st[0][qh], st[1][qh]), vmax4(st[2][qh], st[3][qh]));
                mx[qh] = fmaxf(fmaxf(a[0], a[1]), fmaxf(a[2], a[3]));
#pragma unroll
                for (int n = 0; n < 4; ++n) p[qh][n] = st[n][qh];
            }
        } else {
            mx[0] = -1e30f; mx[1] = -1e30f;
#pragma unroll
            for (int n = 0; n < 4; ++n) {
                unsigned int wd = (n & 2) ? mw.y : mw.x;
#pragma unroll
                for (int r = 0; r < 4; ++r) {
                    int sh = ((n & 1) << 4) + (hi << 2) + r;
                    bool mk = (wd >> sh) & 1u;
#pragma unroll
                    for (int qh = 0; qh < 2; ++qh) {
                        float s = mk ? -1e30f : st[n][qh][r];
                        p[qh][n][r] = s;
                        mx[qh] = fmaxf(mx[qh], s);
                    }
                }
            }
        }
        float m2[2];
#pragma unroll
        for (int qh = 0; qh < 2; ++qh) {
            float v = fmaxf(mx[qh], __shfl_xor(mx[qh], 16));
            m2[qh] = fmaxf(v, __shfl_xor(v, 32));
        }
        float growth = fmaxf(m2[0] - mrow[0], m2[1] - mrow[1]);
        if (!__all(growth <= 8.0f)) {
#pragma unroll
            for (int qh = 0; qh < 2; ++qh) {
                float mnew = fmaxf(mrow[qh], m2[qh]);
                float scl = __builtin_amdgcn_exp2f(mrow[qh] - mnew);
                mrow[qh] = mnew;
                lsum[qh] *= scl;
#pragma unroll
                for (int dt = 0; dt < 4; ++dt)
                    o[dt][qh] *= scl;
            }
        }
#pragma unroll
        for (int qh = 0; qh < 2; ++qh) {
            f32x4 rs4 = zero4;
#pragma unroll
            for (int n = 0; n < 4; ++n) {
                f32x4 e;
#pragma unroll
                for (int r = 0; r < 4; ++r)
                    e[r] = __builtin_amdgcn_exp2f(p[qh][n][r] - mrow[qh]);
                p[qh][n] = e;
                rs4 += e;
            }
            float rs = (rs4[0] + rs4[1]) + (rs4[2] + rs4[3]);
            rs += __shfl_xor(rs, 16);
            rs += __shfl_xor(rs, 32);
            lsum[qh] += rs;
        }
#pragma unroll
        for (int qh = 0; qh < 2; ++qh) {
#pragma unroll
            for (int n = 0; n < 4; ++n) {
                uint2 pk2;
                pk2.x = (unsigned int)f2bf(p[qh][n][0]) | ((unsigned int)f2bf(p[qh][n][1]) << 16);
                pk2.y = (unsigned int)f2bf(p[qh][n][2]) | ((unsigned int)f2bf(p[qh][n][3]) << 16);
                bf16x4 pb = __builtin_bit_cast(bf16x4, pk2);
#pragma unroll
                for (int dt = 0; dt < 4; ++dt)
                    o[dt][qh] = __builtin_amdgcn_mfma_f32_16x16x16bf16_1k(vf[dt][n], pb, o[dt][qh], 0, 0, 0);
            }
        }
        // counted drain: tile tt+1's loads must have landed; tile tt+2's (2 newest) stay in flight
        if (issue) {
            asm volatile("s_waitcnt vmcnt(2)" ::: "memory");
        } else {
            asm volatile("s_waitcnt vmcnt(0)" ::: "memory");
        }
        __builtin_amdgcn_s_barrier();
    }

    // epilogue: O^T -> O via wave-private LDS transpose (8 x 2304 = 18432 <= 24576)
    unsigned short* Tl = &lds[w * 2304];  // [32][72]
    float inv[2] = {1.0f / lsum[0], 1.0f / lsum[1]};
#pragma unroll
    for (int qh = 0; qh < 2; ++qh)
#pragma unroll
        for (int dt = 0; dt < 4; ++dt)
#pragma unroll
            for (int r = 0; r < 4; ++r)
                Tl[(qh * 16 + lo) * 72 + dt * 16 + hi * 4 + r] = f2bf(o[dt][qh][r] * inv[qh]);
#pragma unroll
    for (int ps = 0; ps < 4; ++ps) {
        int row = ps * 8 + (lane >> 3);
        int col = (lane & 7) * 8;
        bf16x8 v = *(const bf16x8*)&Tl[row * 72 + col];
        *(bf16x8*)&Ob[(size_t)(b * S_ + qr0 + row) * DIM_ + h * 64 + col] = v;
    }
}

// ---------------- launch ----------------
extern "C" void kernel_launch(void* const* d_in, const int* in_sizes, int n_in,
                              void* d_out, int out_size, void* d_ws, size_t ws_size,
                              hipStream_t stream)
{
    const float* x  = (const float*)d_in[0];
    const float* cx = (const float*)d_in[1];
    const void* mask = d_in[2];
    const float* Wq = (const float*)d_in[3];
    const float* bq = (const float*)d_in[4];
    const float* Wk = (const float*)d_in[5];
    const float* bk = (const float*)d_in[6];
    const float* Wv = (const float*)d_in[7];
    const float* bv = (const float*)d_in[8];
    const float* Wo = (const float*)d_in[9];
    const float* bo = (const float*)d_in[10];

    unsigned short* ws = (unsigned short*)d_ws;
    const size_t XB  = 0;                                  // 8192*1024 (x bf16; later attn out)
    const size_t CXB = XB  + (size_t)8192 * 1024;          // 4096*768
    const size_t WQT = CXB + (size_t)4096 * 768;           // 1024*1024
    const size_t WKT = WQT + (size_t)1024 * 1024;          // 1024*768  \ contiguous = B^T(2048x768)
    const size_t WVT = WKT + (size_t)1024 * 768;           // 1024*768  /
    const size_t WOT = WVT + (size_t)1024 * 768;           // 1024*1024
    const size_t QB  = WOT + (size_t)1024 * 1024;          // 8192*1024
    const size_t KB  = QB  + (size_t)8192 * 1024;          // 4096*1024
    const size_t VTB = KB  + (size_t)4096 * 1024;          // 4*1024*1024
    const size_t MBT = VTB + (size_t)4 * 1024 * 1024;      // 128 uint32 = 256 ushort
    const size_t NTP = MBT + 256;                          // 4 ints

    unsigned int* mbits = (unsigned int*)(ws + MBT);
    int* ntp = (int*)(ws + NTP);

    k_prep<<<13057, 256, 0, stream>>>(x, ws + XB, cx, ws + CXB,
                                      Wq, Wk, Wv, Wo,
                                      ws + WQT, ws + WKT, ws + WVT, ws + WOT,
                                      (const unsigned int*)mask, mbits, ntp);

    const float QSCALE = 0.125f * 1.44269504088896340736f;  // 1/sqrt(64) * log2(e) folded into Q
    k_gemm_qkv<<<1024, 256, 0, stream>>>(ws + XB, ws + CXB, ws + WQT, ws + WKT,
                                         bq, bk, bv, QSCALE,
                                         ws + QB, ws + KB, ws + VTB);

    dim3 ga(S_ / 256, NH_, B_);
    k_attn<<<ga, 512, 0, stream>>>(ws + QB, ws + KB, ws + VTB, mbits, ntp, ws + XB);

    dim3 go(8192 / 128, 1024 / 128);
    k_gemm_o<<<go, 256, 0, stream>>>(ws + XB, ws + WOT, bo, (float*)d_out, 1024);
}

// Round 16
// 154.370 us; speedup vs baseline: 1.0067x; 1.0067x over previous
//
#include <hip/hip_runtime.h>
#include <hip/hip_bf16.h>
#include <stdint.h>

#define DIM_ 1024
#define NH_ 16
#define HD_ 64
#define B_ 4
#define S_ 2048
#define SC_ 1024
#define CD_ 768

typedef __attribute__((ext_vector_type(8))) short bf16x8;
typedef __attribute__((ext_vector_type(4))) short bf16x4;
typedef __attribute__((ext_vector_type(4))) float f32x4;

// native bf16 cast (RTNE) -- compiler lowers pairs to v_cvt_pk_bf16_f32
__device__ inline unsigned short f2bf(float f) {
    __hip_bfloat16 h = __float2bfloat16(f);
    return __builtin_bit_cast(unsigned short, h);
}

__device__ inline f32x4 vmax4(f32x4 a, f32x4 b) {
    f32x4 r;
#pragma unroll
    for (int i = 0; i < 4; ++i) r[i] = fmaxf(a[i], b[i]);
    return r;
}

#define GLOAD16(SRC, DST) __builtin_amdgcn_global_load_lds( \
    (const __attribute__((address_space(1))) void*)(SRC),   \
    (__attribute__((address_space(3))) void*)(DST), 16, 0, 0)

// ---------------- fused prep: x/cx -> bf16, 4 weight transposes, mask bits ----------------
__global__ void k_prep(const float* __restrict__ x, unsigned short* __restrict__ xb,
                       const float* __restrict__ cx, unsigned short* __restrict__ cxb,
                       const float* __restrict__ Wq, const float* __restrict__ Wk,
                       const float* __restrict__ Wv, const float* __restrict__ Wo,
                       unsigned short* __restrict__ WQT, unsigned short* __restrict__ WKT,
                       unsigned short* __restrict__ WVT, unsigned short* __restrict__ WOT,
                       const unsigned int* __restrict__ m,
                       unsigned int* __restrict__ bits, int* __restrict__ ntp) {
    const int bid = blockIdx.x;
    if (bid < 11264) {  // f32 -> bf16 conversions (uint2 per thread)
        const float* in; unsigned short* out; int i;
        if (bid < 8192) { in = x;  out = xb;  i = bid * 256 + threadIdx.x; }
        else            { in = cx; out = cxb; i = (bid - 8192) * 256 + threadIdx.x; }
        float4 v = ((const float4*)in)[i];
        uint2 pk;
        pk.x = (unsigned int)f2bf(v.x) | ((unsigned int)f2bf(v.y) << 16);
        pk.y = (unsigned int)f2bf(v.z) | ((unsigned int)f2bf(v.w) << 16);
        ((uint2*)out)[i] = pk;
        return;
    }
    if (bid < 13056) {  // weight transposes: one 16B output chunk per thread
        int idx = (bid - 11264) * 256 + threadIdx.x;
        const float* W; unsigned short* WT; int K;
        if (idx < 131072)      { W = Wq; WT = WQT; K = 1024; }
        else if (idx < 229376) { W = Wk; WT = WKT; K = 768;  idx -= 131072; }
        else if (idx < 327680) { W = Wv; WT = WVT; K = 768;  idx -= 229376; }
        else                   { W = Wo; WT = WOT; K = 1024; idx -= 327680; }
        int n = idx & 1023;
        int k0 = (idx >> 10) << 3;
        unsigned int pk[4];
#pragma unroll
        for (int j = 0; j < 4; ++j) {
            unsigned short a = f2bf(W[(size_t)(k0 + 2 * j) * 1024 + n]);
            unsigned short b = f2bf(W[(size_t)(k0 + 2 * j + 1) * 1024 + n]);
            pk[j] = (unsigned int)a | ((unsigned int)b << 16);
        }
        *(uint4*)&WT[(size_t)n * K + k0] = *(uint4*)pk;
        return;
    }
    // mask block: bitmask + nt[b]
    __shared__ int bm_s;
    __shared__ unsigned int wbits[128];
    if (threadIdx.x == 0) bm_s = 0;
    __syncthreads();
    int any = 0;
    for (int i = threadIdx.x; i < 1024; i += 256)  // first 4096 bytes: safe both modes
        if (m[i] > 1u) any = 1;
    if (any) atomicOr(&bm_s, 1);
    __syncthreads();
    const int boolmode = bm_s;
    const int w = threadIdx.x;
    if (w < 128) {
        const unsigned char* mb = (const unsigned char*)m;
        unsigned int out = 0;
        for (int j = 0; j < 32; ++j) {
            int c = w * 32 + j;
            int masked = boolmode ? (mb[c] != 0) : (m[c] != 0u);
            out |= (unsigned int)masked << j;
        }
        bits[w] = out;
        wbits[w] = out;
    }
    __syncthreads();
    if (threadIdx.x < 4) {
        int nt = 0;
        for (int tt = 0; tt < 16; ++tt) {
            unsigned int w0 = wbits[threadIdx.x * 32 + tt * 2];
            unsigned int w1 = wbits[threadIdx.x * 32 + tt * 2 + 1];
            if ((w0 & w1) != 0xFFFFFFFFu) nt = tt + 1;  // tile has >=1 valid key
        }
        ntp[threadIdx.x] = nt;
    }
}

// ---------------- fused Q + K|V GEMM (one launch, 1024 blocks) ----------------
__global__ __launch_bounds__(256) void k_gemm_qkv(
    const unsigned short* __restrict__ xb, const unsigned short* __restrict__ cxb,
    const unsigned short* __restrict__ wqt, const unsigned short* __restrict__ wkt,
    const float* __restrict__ bq, const float* __restrict__ bk, const float* __restrict__ bv,
    float qscale, unsigned short* __restrict__ qb, unsigned short* __restrict__ kb,
    unsigned short* __restrict__ vtb)
{
    __shared__ unsigned short As[2][128 * 64];
    __shared__ unsigned short Bs[2][128 * 64];
    const int t = threadIdx.x;
    const int w = t >> 6, lane = t & 63;
    const int lo = lane & 15, hi = lane >> 4;
    const int l7 = lo & 7;
    const int wg = blockIdx.x;
    const int swz = (wg & 7) * 128 + (wg >> 3);   // 1024 blocks, bijective
    const bool isQ = !(swz & 1);
    const int lw = swz >> 1;                       // 0..511 per kind
    const int gx = isQ ? 64 : 32;
    const unsigned short* A  = isQ ? xb  : cxb;
    const unsigned short* BT = isQ ? wqt : wkt;
    const int K = isQ ? 1024 : 768;
    const int m0 = (lw % gx) * 128, n0 = (lw / gx) * 128;
    const int wr = (w >> 1) * 64, wc = (w & 1) * 64;
    const int srow = lane >> 3;
    const int scb  = ((lane & 7) ^ srow) << 3;

    f32x4 zero4 = {0.f, 0.f, 0.f, 0.f};
    f32x4 acc[4][4];
    for (int i = 0; i < 4; ++i)
        for (int j = 0; j < 4; ++j) acc[i][j] = zero4;

#pragma unroll
    for (int p = 0; p < 4; ++p) {
        int rb = w * 32 + p * 8;
        GLOAD16(&A[(size_t)(m0 + rb + srow) * K + scb], &As[0][rb * 64]);
        GLOAD16(&BT[(size_t)(n0 + rb + srow) * K + scb], &Bs[0][rb * 64]);
    }
    __syncthreads();

    int cur = 0;
    for (int k0 = 0; k0 < K; k0 += 64) {
        if (k0 + 64 < K) {
#pragma unroll
            for (int p = 0; p < 4; ++p) {
                int rb = w * 32 + p * 8;
                GLOAD16(&A[(size_t)(m0 + rb + srow) * K + k0 + 64 + scb], &As[cur ^ 1][rb * 64]);
                GLOAD16(&BT[(size_t)(n0 + rb + srow) * K + k0 + 64 + scb], &Bs[cur ^ 1][rb * 64]);
            }
        }
#pragma unroll
        for (int kk = 0; kk < 2; ++kk) {
            bf16x8 af[4], bfr[4];
#pragma unroll
            for (int i = 0; i < 4; ++i) {
                int row = wr + i * 16 + lo;
                af[i] = *(const bf16x8*)&As[cur][row * 64 + ((((kk << 2) + hi) ^ l7) << 3)];
            }
#pragma unroll
            for (int j = 0; j < 4; ++j) {
                int row = wc + j * 16 + lo;
                bfr[j] = *(const bf16x8*)&Bs[cur][row * 64 + ((((kk << 2) + hi) ^ l7) << 3)];
            }
#pragma unroll
            for (int i = 0; i < 4; ++i)
#pragma unroll
                for (int j = 0; j < 4; ++j)
                    acc[i][j] = __builtin_amdgcn_mfma_f32_16x16x32_bf16(af[i], bfr[j], acc[i][j], 0, 0, 0);
        }
        __syncthreads();
        cur ^= 1;
    }

#pragma unroll
    for (int i = 0; i < 4; ++i) {
#pragma unroll
        for (int j = 0; j < 4; ++j) {
            int n = n0 + wc + j * 16 + lo;
            int mbase = m0 + wr + i * 16 + (hi << 2);
            if (isQ) {
#pragma unroll
                for (int r = 0; r < 4; ++r) {
                    float v = (acc[i][j][r] + bq[n]) * qscale;
                    qb[(size_t)(mbase + r) * 1024 + n] = f2bf(v);
                }
            } else if (n < 1024) {  // K half
#pragma unroll
                for (int r = 0; r < 4; ++r) {
                    float v = acc[i][j][r] + bk[n];
                    kb[(size_t)(mbase + r) * 1024 + n] = f2bf(v);
                }
            } else {                // V^T half: packed 8B store (4 consecutive c)
                float b2 = bv[n - 1024];
                uint2 pk;
                pk.x = (unsigned int)f2bf(acc[i][j][0] + b2) | ((unsigned int)f2bf(acc[i][j][1] + b2) << 16);
                pk.y = (unsigned int)f2bf(acc[i][j][2] + b2) | ((unsigned int)f2bf(acc[i][j][3] + b2) << 16);
                int bb = mbase >> 10, c = mbase & 1023;
                *(uint2*)&vtb[(size_t)((bb << 10) + (n - 1024)) * 1024 + c] = pk;
            }
        }
    }
}

// ---------------- O GEMM (f32 out), BK=64 XOR-swizzled ----------------
__global__ __launch_bounds__(256) void k_gemm_o(
    const unsigned short* __restrict__ A, const unsigned short* __restrict__ BT,
    const float* __restrict__ bias, float* __restrict__ Cf, int K)
{
    __shared__ unsigned short As[2][128 * 64];
    __shared__ unsigned short Bs[2][128 * 64];
    const int t = threadIdx.x;
    const int w = t >> 6, lane = t & 63;
    const int lo = lane & 15, hi = lane >> 4;
    const int l7 = lo & 7;
    const int nwg = gridDim.x * gridDim.y;
    const int wg = blockIdx.y * gridDim.x + blockIdx.x;
    const int swz = (wg & 7) * (nwg >> 3) + (wg >> 3);
    const int m0 = (swz % gridDim.x) * 128, n0 = (swz / gridDim.x) * 128;
    const int wr = (w >> 1) * 64, wc = (w & 1) * 64;
    const int srow = lane >> 3;
    const int scb  = ((lane & 7) ^ srow) << 3;

    f32x4 zero4 = {0.f, 0.f, 0.f, 0.f};
    f32x4 acc[4][4];
    for (int i = 0; i < 4; ++i)
        for (int j = 0; j < 4; ++j) acc[i][j] = zero4;

#pragma unroll
    for (int p = 0; p < 4; ++p) {
        int rb = w * 32 + p * 8;
        GLOAD16(&A[(size_t)(m0 + rb + srow) * K + scb], &As[0][rb * 64]);
        GLOAD16(&BT[(size_t)(n0 + rb + srow) * K + scb], &Bs[0][rb * 64]);
    }
    __syncthreads();

    int cur = 0;
    for (int k0 = 0; k0 < K; k0 += 64) {
        if (k0 + 64 < K) {
#pragma unroll
            for (int p = 0; p < 4; ++p) {
                int rb = w * 32 + p * 8;
                GLOAD16(&A[(size_t)(m0 + rb + srow) * K + k0 + 64 + scb], &As[cur ^ 1][rb * 64]);
                GLOAD16(&BT[(size_t)(n0 + rb + srow) * K + k0 + 64 + scb], &Bs[cur ^ 1][rb * 64]);
            }
        }
#pragma unroll
        for (int kk = 0; kk < 2; ++kk) {
            bf16x8 af[4], bfr[4];
#pragma unroll
            for (int i = 0; i < 4; ++i) {
                int row = wr + i * 16 + lo;
                af[i] = *(const bf16x8*)&As[cur][row * 64 + ((((kk << 2) + hi) ^ l7) << 3)];
            }
#pragma unroll
            for (int j = 0; j < 4; ++j) {
                int row = wc + j * 16 + lo;
                bfr[j] = *(const bf16x8*)&Bs[cur][row * 64 + ((((kk << 2) + hi) ^ l7) << 3)];
            }
#pragma unroll
            for (int i = 0; i < 4; ++i)
#pragma unroll
                for (int j = 0; j < 4; ++j)
                    acc[i][j] = __builtin_amdgcn_mfma_f32_16x16x32_bf16(af[i], bfr[j], acc[i][j], 0, 0, 0);
        }
        __syncthreads();
        cur ^= 1;
    }

#pragma unroll
    for (int i = 0; i < 4; ++i)
#pragma unroll
        for (int j = 0; j < 4; ++j) {
            int n = n0 + wc + j * 16 + lo;
            int mbase = m0 + wr + i * 16 + (hi << 2);
#pragma unroll
            for (int r = 0; r < 4; ++r)
                Cf[(size_t)(mbase + r) * 1024 + n] = acc[i][j][r] + bias[n];
        }
}

// ---------------- fused flash attention: 8 waves x 32 q-rows, KVBLK=128 pair-loop ----------------
// Two 64-KV tiles per barrier: inner body (identical math to R14) runs twice per
// __syncthreads -> per-block barrier convergences halve. Double-buffered pairs
// (64 KB LDS, 2 blocks/CU). Odd-nt overrun tile (< 16) is an exact no-op via the
// bitmask path (fully masked -> P=0, no rescale); K/V data there is valid
// projection output, so reading it is safe.
__global__ __launch_bounds__(512) void k_attn(
    const unsigned short* __restrict__ Q, const unsigned short* __restrict__ Kb,
    const unsigned short* __restrict__ VT, const unsigned int* __restrict__ bits,
    const int* __restrict__ ntp, unsigned short* __restrict__ Ob)
{
    // K: buf c at c*8192, subtile s at +s*4096 -> [0,16384)
    // V: same indexing at +16384 -> [16384,32768). Epilogue reuses [0,18432).
    __shared__ unsigned short lds[32768];
    const int t = threadIdx.x, w = t >> 6, lane = t & 63;
    const int lo = lane & 15, hi = lane >> 4;
    const int qt = blockIdx.x, h = blockIdx.y, b = blockIdx.z;
    const int qr0 = qt * 256 + w * 32;
    const int l7 = lo & 7;
    const int nt = ntp[b];
    const int npairs = (nt + 1) >> 1;

    const int srow = lane >> 3;                 // 0..7 within the wave's 8-row pass
    const int scb  = ((lane & 7) ^ srow) << 3;  // pre-swizzled source 16B block
    const int rl = w * 8 + srow;                // this wave's staging row (0..63)

    bf16x8 qf[2][2];
#pragma unroll
    for (int qh = 0; qh < 2; ++qh)
#pragma unroll
        for (int kk = 0; kk < 2; ++kk)
            qf[qh][kk] = *(const bf16x8*)&Q[(size_t)(b * S_ + qr0 + qh * 16 + lo) * DIM_ + h * 64 + kk * 32 + hi * 8];

    f32x4 zero4 = {0.f, 0.f, 0.f, 0.f};
    float mrow[2] = {-1e30f, -1e30f}, lsum[2] = {0.f, 0.f};
    f32x4 o[4][2];
#pragma unroll
    for (int dt = 0; dt < 4; ++dt)
#pragma unroll
        for (int qh = 0; qh < 2; ++qh) o[dt][qh] = zero4;

    // prologue: stage pair 0 (tiles 0,1) into buf 0 (nt >= 8 always)
#pragma unroll
    for (int s = 0; s < 2; ++s) {
        GLOAD16(&Kb[(size_t)(b * SC_ + s * 64 + rl) * DIM_ + h * 64 + scb],
                &lds[s * 4096 + (w * 8) * 64]);
        GLOAD16(&VT[(size_t)(b * 1024 + h * 64 + rl) * SC_ + s * 64 + scb],
                &lds[16384 + s * 4096 + (w * 8) * 64]);
    }
    __syncthreads();

    int cur = 0;
    for (int p = 0; p < npairs; ++p) {
        if (p + 1 < npairs) {  // stage next pair into other buffer (drains at this iter's barrier)
            int c0n = (p + 1) * 128;
#pragma unroll
            for (int s = 0; s < 2; ++s) {
                GLOAD16(&Kb[(size_t)(b * SC_ + c0n + s * 64 + rl) * DIM_ + h * 64 + scb],
                        &lds[(cur ^ 1) * 8192 + s * 4096 + (w * 8) * 64]);
                GLOAD16(&VT[(size_t)(b * 1024 + h * 64 + rl) * SC_ + c0n + s * 64 + scb],
                        &lds[16384 + (cur ^ 1) * 8192 + s * 4096 + (w * 8) * 64]);
            }
        }
#pragma unroll
        for (int s = 0; s < 2; ++s) {
            const int tt = p * 2 + s;
            const unsigned short* Kl = &lds[cur * 8192 + s * 4096];
            const unsigned short* Vl = &lds[16384 + cur * 8192 + s * 4096];

            f32x4 st[4][2];
#pragma unroll
            for (int n = 0; n < 4; ++n)
#pragma unroll
                for (int qh = 0; qh < 2; ++qh) st[n][qh] = zero4;
#pragma unroll
            for (int n = 0; n < 4; ++n) {
                const int R = n * 16 + lo;
                bf16x8 k0 = *(const bf16x8*)&Kl[R * 64 + ((hi ^ l7) << 3)];
                bf16x8 k1 = *(const bf16x8*)&Kl[R * 64 + (((4 + hi) ^ l7) << 3)];
#pragma unroll
                for (int qh = 0; qh < 2; ++qh) {
                    st[n][qh] = __builtin_amdgcn_mfma_f32_16x16x32_bf16(k0, qf[qh][0], st[n][qh], 0, 0, 0);
                    st[n][qh] = __builtin_amdgcn_mfma_f32_16x16x32_bf16(k1, qf[qh][1], st[n][qh], 0, 0, 0);
                }
            }
            bf16x4 vf[4][4];
#pragma unroll
            for (int dt = 0; dt < 4; ++dt)
#pragma unroll
                for (int n = 0; n < 4; ++n)
                    vf[dt][n] = *(const bf16x4*)&Vl[(dt * 16 + lo) * 64
                                  + (((2 * n + (hi >> 1)) ^ l7) << 3) + ((hi & 1) << 2)];

            uint2 mw = *(const uint2*)&bits[b * 32 + tt * 2];

            f32x4 pp[2][4];
            float mx[2];
            if ((mw.x | mw.y) == 0u) {
#pragma unroll
                for (int qh = 0; qh < 2; ++qh) {
                    f32x4 a = vmax4(vmax4(st[0][qh], st[1][qh]), vmax4(st[2][qh], st[3][qh]));
                    mx[qh] = fmaxf(fmaxf(a[0], a[1]), fmaxf(a[2], a[3]));
#pragma unroll
                    for (int n = 0; n < 4; ++n) pp[qh][n] = st[n][qh];
                }
            } else {
                mx[0] = -1e30f; mx[1] = -1e30f;
#pragma unroll
                for (int n = 0; n < 4; ++n) {
                    unsigned int wd = (n & 2) ? mw.y : mw.x;
#pragma unroll
                    for (int r = 0; r < 4; ++r) {
                        int sh = ((n & 1) << 4) + (hi << 2) + r;
                        bool mk = (wd >> sh) & 1u;
#pragma unroll
                        for (int qh = 0; qh < 2; ++qh) {
                            float sv = mk ? -1e30f : st[n][qh][r];
                            pp[qh][n][r] = sv;
                            mx[qh] = fmaxf(mx[qh], sv);
                        }
                    }
                }
            }
            float m2[2];
#pragma unroll
            for (int qh = 0; qh < 2; ++qh) {
                float v = fmaxf(mx[qh], __shfl_xor(mx[qh], 16));
                m2[qh] = fmaxf(v, __shfl_xor(v, 32));
            }
            float growth = fmaxf(m2[0] - mrow[0], m2[1] - mrow[1]);
            if (!__all(growth <= 8.0f)) {
#pragma unroll
                for (int qh = 0; qh < 2; ++qh) {
                    float mnew = fmaxf(mrow[qh], m2[qh]);
                    float scl = __builtin_amdgcn_exp2f(mrow[qh] - mnew);
                    mrow[qh] = mnew;
                    lsum[qh] *= scl;
#pragma unroll
                    for (int dt = 0; dt < 4; ++dt)
                        o[dt][qh] *= scl;
                }
            }
#pragma unroll
            for (int qh = 0; qh < 2; ++qh) {
                f32x4 rs4 = zero4;
#pragma unroll
                for (int n = 0; n < 4; ++n) {
                    f32x4 e;
#pragma unroll
                    for (int r = 0; r < 4; ++r)
                        e[r] = __builtin_amdgcn_exp2f(pp[qh][n][r] - mrow[qh]);
                    pp[qh][n] = e;
                    rs4 += e;
                }
                float rs = (rs4[0] + rs4[1]) + (rs4[2] + rs4[3]);
                rs += __shfl_xor(rs, 16);
                rs += __shfl_xor(rs, 32);
                lsum[qh] += rs;
            }
#pragma unroll
            for (int qh = 0; qh < 2; ++qh) {
#pragma unroll
                for (int n = 0; n < 4; ++n) {
                    uint2 pk2;
                    pk2.x = (unsigned int)f2bf(pp[qh][n][0]) | ((unsigned int)f2bf(pp[qh][n][1]) << 16);
                    pk2.y = (unsigned int)f2bf(pp[qh][n][2]) | ((unsigned int)f2bf(pp[qh][n][3]) << 16);
                    bf16x4 pb = __builtin_bit_cast(bf16x4, pk2);
#pragma unroll
                    for (int dt = 0; dt < 4; ++dt)
                        o[dt][qh] = __builtin_amdgcn_mfma_f32_16x16x16bf16_1k(vf[dt][n], pb, o[dt][qh], 0, 0, 0);
                }
            }
        }
        __syncthreads();  // drains next-pair vmcnt + all waves' LDS reads of buf[cur]
        cur ^= 1;
    }

    // epilogue: O^T -> O via wave-private LDS transpose (8 x 2304 = 18432 <= 32768)
    unsigned short* Tl = &lds[w * 2304];  // [32][72]
    float inv[2] = {1.0f / lsum[0], 1.0f / lsum[1]};
#pragma unroll
    for (int qh = 0; qh < 2; ++qh)
#pragma unroll
        for (int dt = 0; dt < 4; ++dt)
#pragma unroll
            for (int r = 0; r < 4; ++r)
                Tl[(qh * 16 + lo) * 72 + dt * 16 + hi * 4 + r] = f2bf(o[dt][qh][r] * inv[qh]);
#pragma unroll
    for (int ps = 0; ps < 4; ++ps) {
        int row = ps * 8 + (lane >> 3);
        int col = (lane & 7) * 8;
        bf16x8 v = *(const bf16x8*)&Tl[row * 72 + col];
        *(bf16x8*)&Ob[(size_t)(b * S_ + qr0 + row) * DIM_ + h * 64 + col] = v;
    }
}

// ---------------- launch ----------------
extern "C" void kernel_launch(void* const* d_in, const int* in_sizes, int n_in,
                              void* d_out, int out_size, void* d_ws, size_t ws_size,
                              hipStream_t stream)
{
    const float* x  = (const float*)d_in[0];
    const float* cx = (const float*)d_in[1];
    const void* mask = d_in[2];
    const float* Wq = (const float*)d_in[3];
    const float* bq = (const float*)d_in[4];
    const float* Wk = (const float*)d_in[5];
    const float* bk = (const float*)d_in[6];
    const float* Wv = (const float*)d_in[7];
    const float* bv = (const float*)d_in[8];
    const float* Wo = (const float*)d_in[9];
    const float* bo = (const float*)d_in[10];

    unsigned short* ws = (unsigned short*)d_ws;
    const size_t XB  = 0;                                  // 8192*1024 (x bf16; later attn out)
    const size_t CXB = XB  + (size_t)8192 * 1024;          // 4096*768
    const size_t WQT = CXB + (size_t)4096 * 768;           // 1024*1024
    const size_t WKT = WQT + (size_t)1024 * 1024;          // 1024*768  \ contiguous = B^T(2048x768)
    const size_t WVT = WKT + (size_t)1024 * 768;           // 1024*768  /
    const size_t WOT = WVT + (size_t)1024 * 768;           // 1024*1024
    const size_t QB  = WOT + (size_t)1024 * 1024;          // 8192*1024
    const size_t KB  = QB  + (size_t)8192 * 1024;          // 4096*1024
    const size_t VTB = KB  + (size_t)4096 * 1024;          // 4*1024*1024
    const size_t MBT = VTB + (size_t)4 * 1024 * 1024;      // 128 uint32 = 256 ushort
    const size_t NTP = MBT + 256;                          // 4 ints

    unsigned int* mbits = (unsigned int*)(ws + MBT);
    int* ntp = (int*)(ws + NTP);

    k_prep<<<13057, 256, 0, stream>>>(x, ws + XB, cx, ws + CXB,
                                      Wq, Wk, Wv, Wo,
                                      ws + WQT, ws + WKT, ws + WVT, ws + WOT,
                                      (const unsigned int*)mask, mbits, ntp);

    const float QSCALE = 0.125f * 1.44269504088896340736f;  // 1/sqrt(64) * log2(e) folded into Q
    k_gemm_qkv<<<1024, 256, 0, stream>>>(ws + XB, ws + CXB, ws + WQT, ws + WKT,
                                         bq, bk, bv, QSCALE,
                                         ws + QB, ws + KB, ws + VTB);

    dim3 ga(S_ / 256, NH_, B_);
    k_attn<<<ga, 512, 0, stream>>>(ws + QB, ws + KB, ws + VTB, mbits, ntp, ws + XB);

    dim3 go(8192 / 128, 1024 / 128);
    k_gemm_o<<<go, 256, 0, stream>>>(ws + XB, ws + WOT, bo, (float*)d_out, 1024);
}